// Round 1
// baseline (152.919 us; speedup 1.0000x reference)
//
#include <hip/hip_runtime.h>

// Problem constants (fixed by the reference).
constexpr int S1 = 8, S2 = 8, F = 128;
constexpr int BATCH = 2048;
constexpr int ROWS_PER_BRANCH = S1 * (2 + 2 * S2);   // 144
constexpr int ROWS_PER_B = 2 * ROWS_PER_BRANCH;      // 288
constexpr int ROW_LEN = F + 2;                       // 130
constexpr int TOTAL_ROWS = BATCH * ROWS_PER_B;       // 589824

// One 64-lane wave per output row:
//   out[row][0]       = w_first
//   out[row][1..128]  = features[node][0..127]
//   out[row][129]     = weight
__global__ __launch_bounds__(256) void gae_gather(
    const float* __restrict__ features,
    const float* __restrict__ in_amnt,
    const float* __restrict__ out_amnt,
    const int*   __restrict__ in_sample,
    const int*   __restrict__ out_sample,
    const int*   __restrict__ node_ids,
    float*       __restrict__ out)
{
    const int lane   = threadIdx.x & 63;
    const int wave   = (int)((blockIdx.x * blockDim.x + threadIdx.x) >> 6);
    const int nwaves = (int)((gridDim.x * blockDim.x) >> 6);

    for (int row = wave; row < TOTAL_ROWS; row += nwaves) {
        const int b  = row / ROWS_PER_B;
        const int r  = row - b * ROWS_PER_B;
        const int d1 = r / ROWS_PER_BRANCH;          // 0 = 'in' branch, 1 = 'out'
        const int rr = r - d1 * ROWS_PER_BRANCH;
        const int s1 = rr / 18;
        const int lr = rr - s1 * 18;

        // Hub-1 neighbor (wave-uniform loads -> HW broadcast).
        const int   nid = node_ids[b];
        const int   e1  = nid * S1 + s1;
        const int   n1  = d1 ? out_sample[e1] : in_sample[e1];
        const float w1  = d1 ? out_amnt[e1]   : in_amnt[e1];

        int node; float wf, wt;
        if (lr == 0 || lr == 9) {                    // hub-1 row (appears twice)
            node = n1; wf = w1; wt = w1 * w1;
        } else if (lr <= 8) {                        // hub-2, in-direction
            const int e2 = n1 * S2 + (lr - 1);
            const float w2 = in_amnt[e2];
            node = in_sample[e2]; wf = w2; wt = w2 * w1;
        } else {                                     // hub-2, out-direction
            const int e2 = n1 * S2 + (lr - 10);
            const float w2 = out_amnt[e2];
            node = out_sample[e2]; wf = w2; wt = w2 * w1;
        }

        float*       orow = out      + (size_t)row  * ROW_LEN;
        const float* frow = features + (size_t)node * F;

        // Two coalesced 256B store phases + lane-0 scalars.
        orow[1 + lane]  = frow[lane];
        orow[65 + lane] = frow[64 + lane];
        if (lane == 0) { orow[0] = wf; orow[129] = wt; }
    }
}

extern "C" void kernel_launch(void* const* d_in, const int* in_sizes, int n_in,
                              void* d_out, int out_size, void* d_ws, size_t ws_size,
                              hipStream_t stream) {
    const float* features  = (const float*)d_in[0];
    const float* in_amnt   = (const float*)d_in[1];
    const float* out_amnt  = (const float*)d_in[2];
    const int*   in_sample = (const int*)d_in[3];
    const int*   out_sample= (const int*)d_in[4];
    const int*   node_ids  = (const int*)d_in[5];
    float*       out       = (float*)d_out;

    // 4096 blocks x 256 threads = 16384 waves; 589824/16384 = 36 rows/wave.
    gae_gather<<<4096, 256, 0, stream>>>(features, in_amnt, out_amnt,
                                         in_sample, out_sample, node_ids, out);
}

// Round 2
// 130.090 us; speedup vs baseline: 1.1755x; 1.1755x over previous
//
#include <hip/hip_runtime.h>

// Problem constants (fixed by the reference).
constexpr int S1 = 8, S2 = 8, F = 128;
constexpr int BATCH = 2048;
constexpr int ROWS_PER_BRANCH = S1 * (2 + 2 * S2);   // 144
constexpr int ROWS_PER_B = 2 * ROWS_PER_BRANCH;      // 288
constexpr int ROW_LEN = F + 2;                       // 130
constexpr int TOTAL_ROWS = BATCH * ROWS_PER_B;       // 589824
constexpr int CHUNK = 64;                            // rows per wave-chunk
constexpr int NCHUNKS = TOTAL_ROWS / CHUNK;          // 9216

// Phase 1: each lane resolves ONE row's (node, w_first, w_tail) -> 64
// parallel index chases per wave instead of 1 serialized chase per row.
// Phase 2: wave loops over the 64 rows (node broadcast via __shfl),
// copying the 512B feature row with fully independent iterations.
__global__ __launch_bounds__(256) void gae_gather(
    const float* __restrict__ features,
    const float* __restrict__ in_amnt,
    const float* __restrict__ out_amnt,
    const int*   __restrict__ in_sample,
    const int*   __restrict__ out_sample,
    const int*   __restrict__ node_ids,
    float*       __restrict__ out)
{
    const int lane   = threadIdx.x & 63;
    const int wave   = (int)((blockIdx.x * blockDim.x + threadIdx.x) >> 6);
    const int nwaves = (int)((gridDim.x * blockDim.x) >> 6);

    for (int chunk = wave; chunk < NCHUNKS; chunk += nwaves) {
        const int rowbase = chunk * CHUNK;
        const int row     = rowbase + lane;

        // ---- Phase 1: per-lane index resolution (parallel chase) ----
        const int b  = row / ROWS_PER_B;
        const int r  = row - b * ROWS_PER_B;
        const int d1 = r / ROWS_PER_BRANCH;          // 0='in' branch, 1='out'
        const int rr = r - d1 * ROWS_PER_BRANCH;
        const int s1 = rr / 18;
        const int lr = rr - s1 * 18;

        const int   nid = node_ids[b];
        const int   e1  = nid * S1 + s1;
        const int   n1  = d1 ? out_sample[e1] : in_sample[e1];
        const float w1  = d1 ? out_amnt[e1]   : in_amnt[e1];

        int node; float wf, wt;
        if (lr == 0 || lr == 9) {                    // hub-1 row (twice)
            node = n1; wf = w1; wt = w1 * w1;
        } else if (lr <= 8) {                        // hub-2, in-direction
            const int e2 = n1 * S2 + (lr - 1);
            const float w2 = in_amnt[e2];
            node = in_sample[e2]; wf = w2; wt = w2 * w1;
        } else {                                     // hub-2, out-direction
            const int e2 = n1 * S2 + (lr - 10);
            const float w2 = out_amnt[e2];
            node = out_sample[e2]; wf = w2; wt = w2 * w1;
        }

        float* orow = out + (size_t)row * ROW_LEN;
        orow[0]   = wf;
        orow[129] = wt;

        // ---- Phase 2: broadcast feature copy, independent iterations ----
        #pragma unroll 4
        for (int t = 0; t < CHUNK; ++t) {
            const int nd = __shfl(node, t);
            float*       odst = out      + (size_t)(rowbase + t) * ROW_LEN;
            const float* frow = features + (size_t)nd * F;
            odst[1  + lane] = frow[lane];
            odst[65 + lane] = frow[64 + lane];
        }
    }
}

extern "C" void kernel_launch(void* const* d_in, const int* in_sizes, int n_in,
                              void* d_out, int out_size, void* d_ws, size_t ws_size,
                              hipStream_t stream) {
    const float* features   = (const float*)d_in[0];
    const float* in_amnt    = (const float*)d_in[1];
    const float* out_amnt   = (const float*)d_in[2];
    const int*   in_sample  = (const int*)d_in[3];
    const int*   out_sample = (const int*)d_in[4];
    const int*   node_ids   = (const int*)d_in[5];
    float*       out        = (float*)d_out;

    // 2048 blocks x 256 thr = 8192 waves (8 blocks/CU); 9216 chunks ->
    // each wave does 1-2 chunks via grid-stride.
    gae_gather<<<2048, 256, 0, stream>>>(features, in_amnt, out_amnt,
                                         in_sample, out_sample, node_ids, out);
}

// Round 4
// 128.565 us; speedup vs baseline: 1.1894x; 1.0119x over previous
//
#include <hip/hip_runtime.h>

// Problem constants (fixed by the reference).
constexpr int S1 = 8, S2 = 8, F = 128;
constexpr int BATCH = 2048;
constexpr int ROWS_PER_BRANCH = S1 * (2 + 2 * S2);   // 144
constexpr int ROWS_PER_B = 2 * ROWS_PER_BRANCH;      // 288
constexpr int ROW_LEN = F + 2;                       // 130
constexpr int TOTAL_ROWS = BATCH * ROWS_PER_B;       // 589824
constexpr int CHUNK = 64;                            // rows per wave
constexpr int NCHUNKS = TOTAL_ROWS / CHUNK;          // 9216 (exact)

// Native clang vector type: __builtin_nontemporal_store accepts these
// (HIP's float2 is a class and is rejected).
typedef float f32x2 __attribute__((ext_vector_type(2)));

// Phase 1: each lane resolves ONE row's (node, w_first, w_tail).
// Phase 2: wave loops over the 64 rows; feature row is loaded as f32x2
// per lane, re-paired with one shfl_up so the ENTIRE 130-float output row
// is written as 65 aligned f32x2 nontemporal stores (no L2/L3 pollution).
// Row layout as f32x2 slots: [wf f0][f1 f2]...[f125 f126][f127 wt].
__global__ __launch_bounds__(256) void gae_gather(
    const float* __restrict__ features,
    const float* __restrict__ in_amnt,
    const float* __restrict__ out_amnt,
    const int*   __restrict__ in_sample,
    const int*   __restrict__ out_sample,
    const int*   __restrict__ node_ids,
    float*       __restrict__ out)
{
    const int lane  = threadIdx.x & 63;
    const int chunk = (int)((blockIdx.x * blockDim.x + threadIdx.x) >> 6);
    if (chunk >= NCHUNKS) return;

    const int rowbase = chunk * CHUNK;
    const int row     = rowbase + lane;

    // ---- Phase 1: per-lane index resolution (64 parallel chases) ----
    const int b  = row / ROWS_PER_B;
    const int r  = row - b * ROWS_PER_B;
    const int d1 = r / ROWS_PER_BRANCH;              // 0='in' branch, 1='out'
    const int rr = r - d1 * ROWS_PER_BRANCH;
    const int s1 = rr / 18;
    const int lr = rr - s1 * 18;

    const int   nid = node_ids[b];
    const int   e1  = nid * S1 + s1;
    const int   n1  = d1 ? out_sample[e1] : in_sample[e1];
    const float w1  = d1 ? out_amnt[e1]   : in_amnt[e1];

    int node; float wf, wt;
    if (lr == 0 || lr == 9) {                        // hub-1 row (twice)
        node = n1; wf = w1; wt = w1 * w1;
    } else if (lr <= 8) {                            // hub-2, in-direction
        const int e2 = n1 * S2 + (lr - 1);
        const float w2 = in_amnt[e2];
        node = in_sample[e2]; wf = w2; wt = w2 * w1;
    } else {                                         // hub-2, out-direction
        const int e2 = n1 * S2 + (lr - 10);
        const float w2 = out_amnt[e2];
        node = out_sample[e2]; wf = w2; wt = w2 * w1;
    }

    // ---- Phase 2: broadcast feature copy, f32x2 in / f32x2 nt out ----
    const f32x2* __restrict__ feat2 = (const f32x2*)features;
    #pragma unroll 8
    for (int t = 0; t < CHUNK; ++t) {
        const int   nd  = __shfl(node, t);
        const float wfb = __shfl(wf,  t);
        const float wtb = __shfl(wt,  t);

        const f32x2 fv = feat2[(size_t)nd * (F / 2) + lane];  // f[2L], f[2L+1]
        const float lo = __shfl_up(fv.y, 1);                  // f[2L-1]

        f32x2* orow2 = (f32x2*)(out + (size_t)(rowbase + t) * ROW_LEN);
        f32x2 slot;
        slot.x = (lane == 0) ? wfb : lo;                      // f[2L-1] | wf
        slot.y = fv.x;                                        // f[2L]
        __builtin_nontemporal_store(slot, &orow2[lane]);
        if (lane == 63) {
            f32x2 tail; tail.x = fv.y; tail.y = wtb;          // f127, wt
            __builtin_nontemporal_store(tail, &orow2[64]);
        }
    }
}

extern "C" void kernel_launch(void* const* d_in, const int* in_sizes, int n_in,
                              void* d_out, int out_size, void* d_ws, size_t ws_size,
                              hipStream_t stream) {
    const float* features   = (const float*)d_in[0];
    const float* in_amnt    = (const float*)d_in[1];
    const float* out_amnt   = (const float*)d_in[2];
    const int*   in_sample  = (const int*)d_in[3];
    const int*   out_sample = (const int*)d_in[4];
    const int*   node_ids   = (const int*)d_in[5];
    float*       out        = (float*)d_out;

    // 2304 blocks x 4 waves = 9216 waves == NCHUNKS: exactly one 64-row
    // chunk per wave, no grid-stride tail imbalance.
    gae_gather<<<2304, 256, 0, stream>>>(features, in_amnt, out_amnt,
                                         in_sample, out_sample, node_ids, out);
}